// Round 6
// baseline (45.189 us; speedup 1.0000x reference)
//
#include <hip/hip_runtime.h>
#include <stddef.h>

#define NB 4
#define NP 160
#define NL 128
#define NH 768
#define NT 9
#define NBLK (NB * NL)   // 512, one block per (b,l)
#define L2E 1.4426950408889634f
#define LN2 0.6931471805599453f

struct WS {
    float    lg[NBLK * NT];   // logits rows (agent-scope stores), 16B aligned
    float    part[NBLK];      // per-block slice mins (agent-scope)
    unsigned flags[NBLK];     // 0 = producer wrote row; 1 = bias-only; 2 = minv fixup
    unsigned counter;         // arrival counter, zeroed by memset node each call
};

#define AST(p, v) __hip_atomic_store((p), (v), __ATOMIC_RELAXED, __HIP_MEMORY_SCOPE_AGENT)
#define ALD(p)    __hip_atomic_load((p), __ATOMIC_RELAXED, __HIP_MEMORY_SCOPE_AGENT)

__device__ __forceinline__ float rdlane(float v, int p) {
    return __int_as_float(__builtin_amdgcn_readlane(__float_as_int(v), p));
}

// Full-wave sum via DPP; result in lane 63.
__device__ __forceinline__ float dpp_add(float x) {
    float t;
#define STEP(ctrl, rmask, bc) \
    t = __int_as_float(__builtin_amdgcn_update_dpp(0, __float_as_int(x), ctrl, rmask, 0xf, bc)); \
    x += t;
    STEP(0x111, 0xf, true) STEP(0x112, 0xf, true) STEP(0x114, 0xf, true) STEP(0x118, 0xf, true)
    STEP(0x142, 0xa, false) STEP(0x143, 0xc, false)
#undef STEP
    return x;
}

// Full-wave min via DPP; result in lane 63.
__device__ __forceinline__ float dpp_fmin(float x) {
    float t;
#define STEP(ctrl, rmask) \
    t = __int_as_float(__builtin_amdgcn_update_dpp(__float_as_int(x), __float_as_int(x), ctrl, rmask, 0xf, false)); \
    x = fminf(x, t);
    STEP(0x111, 0xf) STEP(0x112, 0xf) STEP(0x114, 0xf) STEP(0x118, 0xf)
    STEP(0x142, 0xa) STEP(0x143, 0xc)
#undef STEP
    return x;
}

__global__ __launch_bounds__(256) void kfused(
    const float* __restrict__ embs, const void* __restrict__ p2w,
    const void* __restrict__ masks, const int* __restrict__ labels,
    const int* __restrict__ sentlen, const float* __restrict__ W,
    const float* __restrict__ bias, const float* __restrict__ start_t,
    const float* __restrict__ end_t, const float* __restrict__ trans,
    float* __restrict__ out, WS* __restrict__ ws)
{
    const int bl = blockIdx.x;        // 0..511
    const int b  = bl / NL;
    const int tid = threadIdx.x;

    __shared__ float wrsh[NH];
    __shared__ int   plist[NP];
    __shared__ int   cnt;
    __shared__ int   isint_sh;
    __shared__ float wmin[4];
    __shared__ int   amlast;

    // ---------- phase 1: producer (all 512 blocks) ----------
    // early independent loads
    const float4* e4 = (const float4*)(embs + bl * 960);   // 512*960 = NB*NP*NH; 16B aligned
    float4 mv4 = (tid < 240) ? e4[tid] : make_float4(3.0e38f, 3.0e38f, 3.0e38f, 3.0e38f);
    unsigned char pb = 0;
    if (tid < NP) pb = ((const unsigned char*)p2w)[bl * NP + tid];   // in-bounds either storage
    const unsigned char mkb = ((const unsigned char*)masks)[bl];

    // detect: masks word 0 (batch 0 all-true): int32 -> 1, bytes -> 0x01010101
    if (tid == 0) { isint_sh = (((const unsigned*)masks)[0] <= 1u); cnt = 0; }
    __syncthreads();
    const int is_int = isint_sh;

    int have = 0;
    if (tid < NP) have = is_int ? (((const int*)p2w)[bl * NP + tid] != 0) : (pb != 0);
    if (have) plist[atomicAdd(&cnt, 1)] = tid;

    float m = fminf(fminf(mv4.x, mv4.y), fminf(mv4.z, mv4.w));
    m = dpp_fmin(m);
    if ((tid & 63) == 63) wmin[tid >> 6] = m;

    const int mk = is_int ? (((const int*)masks)[bl] != 0) : (mkb != 0);
    __syncthreads();
    if (tid == 0) {
        float pm = fminf(fminf(wmin[0], wmin[1]), fminf(wmin[2], wmin[3]));
        AST(&ws->part[bl], pm);
    }

    const int nc = cnt;
    if (nc == 0) {
        // consumer writes these rows (single-writer discipline for d_out)
        if (tid == 0) AST(&ws->flags[bl], mk ? 2u : 1u);
    } else {
        if (tid == 0) AST(&ws->flags[bl], 0u);
        #pragma unroll
        for (int k = 0; k < 3; k++) {
            int h = tid + k * 256;
            float wr = -3.0e38f;      // min_value <= all values, so -inf init equivalent
            for (int i = 0; i < nc; i++)
                wr = fmaxf(wr, embs[(b * NP + plist[i]) * NH + h]);
            wrsh[h] = mk ? wr : 0.f;
        }
        __syncthreads();
        const int w = tid >> 6, lane = tid & 63;
        for (int t = w; t < NT; t += 4) {
            float acc = 0.f;
            #pragma unroll
            for (int j = 0; j < 12; j++) acc += wrsh[lane + j * 64] * W[(lane + j * 64) * NT + t];
            acc = dpp_add(acc);
            if (lane == 63) {
                float v = acc + bias[t];
                out[1 + bl * NT + t] = v;   // normal store (end-of-kernel flush covers host)
                AST(&ws->lg[bl * NT + t], v);
            }
        }
    }

    // ---------- arrival: drain this wave's stores, then relaxed counter ----------
    asm volatile("s_waitcnt vmcnt(0)" ::: "memory");
    __syncthreads();                  // every wave drained before any proceeds
    if (tid == 0) {
        unsigned old = __hip_atomic_fetch_add(&ws->counter, 1u, __ATOMIC_RELAXED,
                                              __HIP_MEMORY_SCOPE_AGENT);
        amlast = (old == NBLK - 1);
    }
    __syncthreads();
    if (!amlast) return;

    // ---------- phase 2: consumer (the 512th arriver) ----------
    __shared__ float em_s[NB * NL * NT + 16];   // raw logits; pad for prefetch overread
    __shared__ float trs[NT * NT];              // log2-scaled
    __shared__ int   lab_s[NB * NL];
    __shared__ float llh[NB];
    __shared__ float colsum[NT];
    __shared__ float wmin2[4];

    const int w    = tid >> 6;
    const int lane = tid & 63;

    {   // global min from 512 partials (agent loads -> IF)
        float mv = fminf(ALD(&ws->part[tid]), ALD(&ws->part[tid + 256]));
        mv = dpp_fmin(mv);
        if (lane == 63) wmin2[w] = mv;
    }
    for (int t = w; t < NT; t += 4) {   // colsum(W)
        float s = 0.f;
        #pragma unroll
        for (int j = 0; j < 12; j++) s += W[(lane + j * 64) * NT + t];
        s = dpp_add(s);
        if (lane == 63) colsum[t] = s;
    }
    {   // stage logits: 8B agent loads (2304 u64, 9 rounds)
        const unsigned long long* lg8 = (const unsigned long long*)ws->lg;
        for (int i = tid; i < (NBLK * NT) / 2; i += 256) {
            unsigned long long v = ALD(&lg8[i]);
            em_s[2 * i]     = __int_as_float((unsigned)v);
            em_s[2 * i + 1] = __int_as_float((unsigned)(v >> 32));
        }
    }
    if (tid < (NB * NL) / 4) ((int4*)lab_s)[tid] = ((const int4*)labels)[tid];
    if (tid < NT * NT) trs[tid] = trans[tid] * L2E;
    __syncthreads();

    const float minv = fminf(fminf(wmin2[0], wmin2[1]), fminf(wmin2[2], wmin2[3]));

    // fix flagged rows: 1 -> bias-only, 2 -> minv*colsum + bias (em_s + d_out)
    for (int r = tid; r < NBLK; r += 256) {
        unsigned f = ALD(&ws->flags[r]);
        if (f) {
            #pragma unroll
            for (int t = 0; t < NT; t++) {
                float v = (f == 2u) ? fmaf(minv, colsum[t], bias[t]) : bias[t];
                em_s[r * NT + t]    = v;
                out[1 + r * NT + t] = v;
            }
        }
    }
    __syncthreads();

    // ---- CRF: one wave per batch, lanes 0..8 hold alpha[tag], log2 domain ----
    const int bb  = w;
    const int c   = (lane < NT) ? lane : 0;
    const int len = sentlen[bb];                // masks == arange < sent_length
    const float* em  = em_s + bb * NL * NT;
    const int*   lab = lab_s + bb * NL;

    // numerator: fully parallel over positions
    float nsum = 0.f;
    for (int i = 1 + lane; i < len; i += 64) {
        int tp = lab[i - 1], tc = lab[i];
        nsum = fmaf(em[i * NT + tc], L2E, nsum + trs[tp * NT + tc]);
    }
    nsum = dpp_add(nsum);
    const float nsum_all = rdlane(nsum, 63);

    float tcol[NT];
    #pragma unroll
    for (int p = 0; p < NT; p++) tcol[p] = trs[p * NT + c];

    float a    = fmaf(em[c], L2E, start_t[c] * L2E);
    float em_c = em[NT + c];
    for (int i = 1; i < len; i++) {
        float em_nx = em[(i + 1) * NT + c];     // pad covers overread at i = len-1
        float v0 = rdlane(a, 0) + tcol[0];
        float e[8];
        #pragma unroll
        for (int p = 1; p < NT; p++) {
            float d = (rdlane(a, p) + tcol[p]) - v0;
            asm("v_exp_f32 %0, %1" : "=v"(e[p - 1]) : "v"(d));
        }
        float s = 1.0f + (((e[0] + e[1]) + (e[2] + e[3])) + ((e[4] + e[5]) + (e[6] + e[7])));
        float lg;
        asm("v_log_f32 %0, %1" : "=v"(lg) : "v"(s));
        a = fmaf(em_c, L2E, v0 + lg);
        em_c = em_nx;
    }

    float xv = a + end_t[c] * L2E;
    if (lane == 0) {
        float dv[NT];
        #pragma unroll
        for (int p = 0; p < NT; p++) dv[p] = rdlane(xv, p);
        float mx = fmaxf(fmaxf(fmaxf(dv[0], dv[1]), dv[2]),
                         fmaxf(fmaxf(fmaxf(dv[3], dv[4]), dv[5]),
                               fmaxf(fmaxf(dv[6], dv[7]), dv[8])));
        float s = 0.f;
        #pragma unroll
        for (int p = 0; p < NT; p++) {
            float d = dv[p] - mx, ee;
            asm("v_exp_f32 %0, %1" : "=v"(ee) : "v"(d));
            s += ee;
        }
        float lg;
        asm("v_log_f32 %0, %1" : "=v"(lg) : "v"(s));
        float den = mx + lg;
        int   t0  = lab[0];
        float num = fmaf(em[t0], L2E, nsum_all + start_t[t0] * L2E + end_t[lab[len - 1]] * L2E);
        llh[bb] = (num - den) * LN2;
    }
    __syncthreads();
    if (tid == 0) out[0] = -(llh[0] + llh[1] + llh[2] + llh[3]);
}

extern "C" void kernel_launch(void* const* d_in, const int* in_sizes, int n_in,
                              void* d_out, int out_size, void* d_ws, size_t ws_size,
                              hipStream_t stream) {
    const float* embs    = (const float*)d_in[0];
    const void*  p2w     = d_in[1];
    const void*  masks   = d_in[2];
    const int*   labels  = (const int*)d_in[3];
    const int*   sentlen = (const int*)d_in[4];
    const float* W       = (const float*)d_in[5];
    const float* bias    = (const float*)d_in[6];
    const float* start_t = (const float*)d_in[7];
    const float* end_t   = (const float*)d_in[8];
    const float* trans   = (const float*)d_in[9];

    float* out = (float*)d_out;        // out[0] = loss, out[1..] = logits (B,L,T)
    WS*    ws  = (WS*)d_ws;

    hipMemsetAsync((char*)d_ws + offsetof(WS, counter), 0, sizeof(unsigned), stream);
    kfused<<<NBLK, 256, 0, stream>>>(embs, p2w, masks, labels, sentlen, W, bias,
                                     start_t, end_t, trans, out, ws);
}

// Round 7
// 41.740 us; speedup vs baseline: 1.0826x; 1.0826x over previous
//
#include <hip/hip_runtime.h>
#include <stddef.h>

#define NB 4
#define NP 160
#define NL 128
#define NH 768
#define NT 9
#define NBLK (NB * NL)   // 512 producer blocks, one per (b,l); block 512 = consumer
#define NLEAF 32
#define L2E 1.4426950408889634f
#define LN2 0.6931471805599453f

struct WS {
    float    lg[NBLK * NT];   // logits rows (agent-scope, cache-bypass)
    float    part[NBLK];      // per-block slice mins
    unsigned flags[NBLK];     // 0 = producer wrote row; 1 = bias-only; 2 = minv fixup
    unsigned root;            // arrival root counter   (memset to 0 each call)
    unsigned leaf[NLEAF];     // arrival leaf counters  (memset to 0 each call)
};

#define AST(p, v) __hip_atomic_store((p), (v), __ATOMIC_RELAXED, __HIP_MEMORY_SCOPE_AGENT)
#define ALD(p)    __hip_atomic_load((p), __ATOMIC_RELAXED, __HIP_MEMORY_SCOPE_AGENT)

__device__ __forceinline__ float rdlane(float v, int p) {
    return __int_as_float(__builtin_amdgcn_readlane(__float_as_int(v), p));
}

// Full-wave sum via DPP; result in lane 63.
__device__ __forceinline__ float dpp_add(float x) {
    float t;
#define STEP(ctrl, rmask, bc) \
    t = __int_as_float(__builtin_amdgcn_update_dpp(0, __float_as_int(x), ctrl, rmask, 0xf, bc)); \
    x += t;
    STEP(0x111, 0xf, true) STEP(0x112, 0xf, true) STEP(0x114, 0xf, true) STEP(0x118, 0xf, true)
    STEP(0x142, 0xa, false) STEP(0x143, 0xc, false)
#undef STEP
    return x;
}

// Full-wave min via DPP; result in lane 63.
__device__ __forceinline__ float dpp_fmin(float x) {
    float t;
#define STEP(ctrl, rmask) \
    t = __int_as_float(__builtin_amdgcn_update_dpp(__float_as_int(x), __float_as_int(x), ctrl, rmask, 0xf, false)); \
    x = fminf(x, t);
    STEP(0x111, 0xf) STEP(0x112, 0xf) STEP(0x114, 0xf) STEP(0x118, 0xf)
    STEP(0x142, 0xa) STEP(0x143, 0xc)
#undef STEP
    return x;
}

__global__ __launch_bounds__(256) void kfused(
    const float* __restrict__ embs, const void* __restrict__ p2w,
    const void* __restrict__ masks, const int* __restrict__ labels,
    const int* __restrict__ sentlen, const float* __restrict__ W,
    const float* __restrict__ bias, const float* __restrict__ start_t,
    const float* __restrict__ end_t, const float* __restrict__ trans,
    float* __restrict__ out, WS* __restrict__ ws)
{
    const int bl  = blockIdx.x;       // 0..511 producers, 512 consumer
    const int tid = threadIdx.x;

    // shared for both roles (union-by-max via kernel scope)
    __shared__ float wrsh[NH];
    __shared__ int   plist[NP];
    __shared__ int   cnt;
    __shared__ int   isint_sh;
    __shared__ float wmin[4];
    __shared__ float em_s[NB * NL * NT + 16];   // raw logits; pad for prefetch overread
    __shared__ float trs[NT * NT];              // log2-scaled
    __shared__ int   lab_s[NB * NL];
    __shared__ float llh[NB];
    __shared__ float colsum[NT];

    const int w    = tid >> 6;
    const int lane = tid & 63;

    if (bl < NBLK) {
        // ================= producer =================
        const int b = bl / NL;

        const float4* e4 = (const float4*)(embs + bl * 960);   // 512*960 = NB*NP*NH
        float4 mv4 = (tid < 240) ? e4[tid] : make_float4(3.0e38f, 3.0e38f, 3.0e38f, 3.0e38f);
        unsigned char pb = 0;
        if (tid < NP) pb = ((const unsigned char*)p2w)[bl * NP + tid];
        const unsigned char mkb = ((const unsigned char*)masks)[bl];

        // detect: masks word 0 (batch 0 all-true): int32 -> 1, bytes -> 0x01010101
        if (tid == 0) { isint_sh = (((const unsigned*)masks)[0] <= 1u); cnt = 0; }
        __syncthreads();
        const int is_int = isint_sh;

        int have = 0;
        if (tid < NP) have = is_int ? (((const int*)p2w)[bl * NP + tid] != 0) : (pb != 0);
        if (have) plist[atomicAdd(&cnt, 1)] = tid;

        float m = fminf(fminf(mv4.x, mv4.y), fminf(mv4.z, mv4.w));
        m = dpp_fmin(m);
        if (lane == 63) wmin[w] = m;

        const int mk = is_int ? (((const int*)masks)[bl] != 0) : (mkb != 0);
        __syncthreads();
        if (tid == 0) {
            float pm = fminf(fminf(wmin[0], wmin[1]), fminf(wmin[2], wmin[3]));
            AST(&ws->part[bl], pm);
        }

        const int nc = cnt;
        if (nc == 0) {
            if (tid == 0) AST(&ws->flags[bl], mk ? 2u : 1u);   // consumer writes these rows
        } else {
            if (tid == 0) AST(&ws->flags[bl], 0u);
            #pragma unroll
            for (int k = 0; k < 3; k++) {
                int h = tid + k * 256;
                float wr = -3.0e38f;          // min_value <= all values: -inf init equivalent
                for (int i = 0; i < nc; i++)
                    wr = fmaxf(wr, embs[(b * NP + plist[i]) * NH + h]);
                wrsh[h] = mk ? wr : 0.f;
            }
            __syncthreads();
            for (int t = w; t < NT; t += 4) {
                float acc = 0.f;
                #pragma unroll
                for (int j = 0; j < 12; j++)
                    acc += wrsh[lane + j * 64] * W[(lane + j * 64) * NT + t];
                acc = dpp_add(acc);
                if (lane == 63) {
                    float v = acc + bias[t];
                    out[1 + bl * NT + t] = v;
                    AST(&ws->lg[bl * NT + t], v);
                }
            }
        }

        // ---- arrival: drain stores, then hierarchical counters (16 per leaf, 32 leaves) ----
        asm volatile("s_waitcnt vmcnt(0)" ::: "memory");
        __syncthreads();
        if (tid == 0) {
            unsigned old = __hip_atomic_fetch_add(&ws->leaf[bl & (NLEAF - 1)], 1u,
                                                  __ATOMIC_RELAXED, __HIP_MEMORY_SCOPE_AGENT);
            if (old == (NBLK / NLEAF) - 1)
                __hip_atomic_fetch_add(&ws->root, 1u, __ATOMIC_RELAXED,
                                       __HIP_MEMORY_SCOPE_AGENT);
        }
        return;
    }

    // ================= consumer (block 512) =================
    // prestage independent data while producers run
    if (tid < (NB * NL) / 4) ((int4*)lab_s)[tid] = ((const int4*)labels)[tid];
    if (tid < NT * NT) trs[tid] = trans[tid] * L2E;
    for (int t = w; t < NT; t += 4) {   // colsum(W) for minv fixup
        float s = 0.f;
        #pragma unroll
        for (int j = 0; j < 12; j++) s += W[(lane + j * 64) * NT + t];
        s = dpp_add(s);
        if (lane == 63) colsum[t] = s;
    }

    // spin until all 512 producers arrived
    if (tid == 0) {
        while (ALD(&ws->root) < NLEAF) __builtin_amdgcn_s_sleep(8);
    }
    __syncthreads();

    __shared__ float wmin2[4];
    {   // global min from 512 partials
        float mv = fminf(ALD(&ws->part[tid]), ALD(&ws->part[tid + 256]));
        mv = dpp_fmin(mv);
        if (lane == 63) wmin2[w] = mv;
    }
    {   // stage logits: 8B cache-bypass loads (2304 u64, 9 independent rounds)
        const unsigned long long* lg8 = (const unsigned long long*)ws->lg;
        #pragma unroll
        for (int r = 0; r < 9; r++) {
            int i = tid + r * 256;
            unsigned long long v = ALD(&lg8[i]);
            em_s[2 * i]     = __int_as_float((unsigned)v);
            em_s[2 * i + 1] = __int_as_float((unsigned)(v >> 32));
        }
    }
    __syncthreads();
    const float minv = fminf(fminf(wmin2[0], wmin2[1]), fminf(wmin2[2], wmin2[3]));

    // fix flagged rows: 1 -> bias-only, 2 -> minv*colsum + bias (em_s + d_out)
    for (int r = tid; r < NBLK; r += 256) {
        unsigned f = ALD(&ws->flags[r]);
        if (f) {
            #pragma unroll
            for (int t = 0; t < NT; t++) {
                float v = (f == 2u) ? fmaf(minv, colsum[t], bias[t]) : bias[t];
                em_s[r * NT + t]    = v;
                out[1 + r * NT + t] = v;
            }
        }
    }
    __syncthreads();

    // ---- CRF: one wave per batch, lanes 0..8 hold alpha[tag], log2 domain ----
    const int bb  = w;
    const int c   = (lane < NT) ? lane : 0;
    const int len = sentlen[bb];                // masks == arange < sent_length
    const float* em  = em_s + bb * NL * NT;
    const int*   lab = lab_s + bb * NL;

    float nsum = 0.f;
    for (int i = 1 + lane; i < len; i += 64) {
        int tp = lab[i - 1], tc = lab[i];
        nsum = fmaf(em[i * NT + tc], L2E, nsum + trs[tp * NT + tc]);
    }
    nsum = dpp_add(nsum);
    const float nsum_all = rdlane(nsum, 63);

    float tcol[NT];
    #pragma unroll
    for (int p = 0; p < NT; p++) tcol[p] = trs[p * NT + c];

    float a    = fmaf(em[c], L2E, start_t[c] * L2E);
    float em_c = em[NT + c];
    for (int i = 1; i < len; i++) {
        float em_nx = em[(i + 1) * NT + c];     // pad covers overread at i = len-1
        float v0 = rdlane(a, 0) + tcol[0];
        float e[8];
        #pragma unroll
        for (int p = 1; p < NT; p++) {
            float d = (rdlane(a, p) + tcol[p]) - v0;
            asm("v_exp_f32 %0, %1" : "=v"(e[p - 1]) : "v"(d));
        }
        float s = 1.0f + (((e[0] + e[1]) + (e[2] + e[3])) + ((e[4] + e[5]) + (e[6] + e[7])));
        float lg;
        asm("v_log_f32 %0, %1" : "=v"(lg) : "v"(s));
        a = fmaf(em_c, L2E, v0 + lg);
        em_c = em_nx;
    }

    float xv = a + end_t[c] * L2E;
    if (lane == 0) {
        float dv[NT];
        #pragma unroll
        for (int p = 0; p < NT; p++) dv[p] = rdlane(xv, p);
        float mx = fmaxf(fmaxf(fmaxf(dv[0], dv[1]), dv[2]),
                         fmaxf(fmaxf(fmaxf(dv[3], dv[4]), dv[5]),
                               fmaxf(fmaxf(dv[6], dv[7]), dv[8])));
        float s = 0.f;
        #pragma unroll
        for (int p = 0; p < NT; p++) {
            float d = dv[p] - mx, ee;
            asm("v_exp_f32 %0, %1" : "=v"(ee) : "v"(d));
            s += ee;
        }
        float lg;
        asm("v_log_f32 %0, %1" : "=v"(lg) : "v"(s));
        float den = mx + lg;
        int   t0  = lab[0];
        float num = fmaf(em[t0], L2E, nsum_all + start_t[t0] * L2E + end_t[lab[len - 1]] * L2E);
        llh[bb] = (num - den) * LN2;
    }
    __syncthreads();
    if (tid == 0) out[0] = -(llh[0] + llh[1] + llh[2] + llh[3]);
}

extern "C" void kernel_launch(void* const* d_in, const int* in_sizes, int n_in,
                              void* d_out, int out_size, void* d_ws, size_t ws_size,
                              hipStream_t stream) {
    const float* embs    = (const float*)d_in[0];
    const void*  p2w     = d_in[1];
    const void*  masks   = d_in[2];
    const int*   labels  = (const int*)d_in[3];
    const int*   sentlen = (const int*)d_in[4];
    const float* W       = (const float*)d_in[5];
    const float* bias    = (const float*)d_in[6];
    const float* start_t = (const float*)d_in[7];
    const float* end_t   = (const float*)d_in[8];
    const float* trans   = (const float*)d_in[9];

    float* out = (float*)d_out;        // out[0] = loss, out[1..] = logits (B,L,T)
    WS*    ws  = (WS*)d_ws;

    // zero root + leaf counters (contiguous), one tiny node
    hipMemsetAsync((char*)d_ws + offsetof(WS, root), 0, (1 + NLEAF) * sizeof(unsigned), stream);
    kfused<<<NBLK + 1, 256, 0, stream>>>(embs, p2w, masks, labels, sentlen, W, bias,
                                         start_t, end_t, trans, out, ws);
}

// Round 8
// 29.363 us; speedup vs baseline: 1.5390x; 1.4215x over previous
//
#include <hip/hip_runtime.h>

#define NB 4
#define NP 160
#define NL 128
#define NH 768
#define NT 9
#define NBLK (NB * NL)   // 512, one block per (b,l)
#define L2E 1.4426950408889634f
#define LN2 0.6931471805599453f

struct WS {
    float lg[NBLK * NT];   // 16B-aligned logits copy for fast kcrf staging
    float part[NBLK];      // per-block slice mins of embs
    int   empty[NBLK];     // 1 = empty-but-masked row (needs minv fixup in kcrf)
};

__device__ __forceinline__ float rdlane(float v, int p) {
    return __int_as_float(__builtin_amdgcn_readlane(__float_as_int(v), p));
}

// Full-wave sum via DPP; result in lane 63.
__device__ __forceinline__ float dpp_add(float x) {
    float t;
#define STEP(ctrl, rmask, bc) \
    t = __int_as_float(__builtin_amdgcn_update_dpp(0, __float_as_int(x), ctrl, rmask, 0xf, bc)); \
    x += t;
    STEP(0x111, 0xf, true) STEP(0x112, 0xf, true) STEP(0x114, 0xf, true) STEP(0x118, 0xf, true)
    STEP(0x142, 0xa, false) STEP(0x143, 0xc, false)
#undef STEP
    return x;
}

// Full-wave min via DPP; result in lane 63.
__device__ __forceinline__ float dpp_fmin(float x) {
    float t;
#define STEP(ctrl, rmask) \
    t = __int_as_float(__builtin_amdgcn_update_dpp(__float_as_int(x), __float_as_int(x), ctrl, rmask, 0xf, false)); \
    x = fminf(x, t);
    STEP(0x111, 0xf) STEP(0x112, 0xf) STEP(0x114, 0xf) STEP(0x118, 0xf)
    STEP(0x142, 0xa) STEP(0x143, 0xc)
#undef STEP
    return x;
}

__device__ __forceinline__ float exp2v(float x) {
    float r; asm("v_exp_f32 %0, %1" : "=v"(r) : "v"(x)); return r;
}

// ---------------- Kernel 1: word pooling + logits (+ slice-min, + dtype detect) -------
__global__ __launch_bounds__(256) void klogits(
    const float* __restrict__ embs, const void* __restrict__ p2w,
    const void* __restrict__ masks, const float* __restrict__ W,
    const float* __restrict__ bias, float* __restrict__ out_logits, WS* __restrict__ ws)
{
    const int bl = blockIdx.x;        // 0..511
    const int b  = bl / NL;
    const int tid = threadIdx.x;
    const int w = tid >> 6, lane = tid & 63;

    __shared__ float wrsh[NH];
    __shared__ int   isint_sh;
    __shared__ float wmin[4];
    __shared__ unsigned long long balsh[4];

    // ---- early independent loads ----
    const float4* e4 = (const float4*)(embs + bl * 960);   // 512*960 = NB*NP*NH
    float4 mv4 = (tid < 240) ? e4[tid] : make_float4(3.0e38f, 3.0e38f, 3.0e38f, 3.0e38f);
    unsigned char pb = 0;
    if (tid < NP) pb = ((const unsigned char*)p2w)[bl * NP + tid];
    const unsigned char mkb = ((const unsigned char*)masks)[bl];

    // detect: masks word 0 (batch 0 all-true): int32 -> 1, bytes -> 0x01010101
    if (tid == 0) isint_sh = (((const unsigned*)masks)[0] <= 1u);
    __syncthreads();
    const int is_int = isint_sh;

    // pieces for a word are one contiguous run -> first/last via ballots (no atomics)
    int have = 0;
    if (tid < NP) have = is_int ? (((const int*)p2w)[bl * NP + tid] != 0) : (pb != 0);
    unsigned long long bal = __ballot(have != 0);
    if (lane == 0) balsh[w] = bal;

    float m = fminf(fminf(mv4.x, mv4.y), fminf(mv4.z, mv4.w));
    m = dpp_fmin(m);
    if (lane == 63) wmin[w] = m;

    const int mk = is_int ? (((const int*)masks)[bl] != 0) : (mkb != 0);
    __syncthreads();
    if (tid == 0) ws->part[bl] = fminf(fminf(wmin[0], wmin[1]), fminf(wmin[2], wmin[3]));

    unsigned long long b0 = balsh[0], b1 = balsh[1], b2 = balsh[2];
    int first = b0 ? (__ffsll((long long)b0) - 1)
              : b1 ? (63 + __ffsll((long long)b1))
              : b2 ? (127 + __ffsll((long long)b2)) : -1;
    int last  = b2 ? (191 - __clzll((long long)b2))
              : b1 ? (127 - __clzll((long long)b1))
              : b0 ? (63 - __clzll((long long)b0)) : -1;

    if (first < 0) {
        // masked+empty -> word_reps = min_value (kcrf fixes); else zeros -> bias only
        if (tid == 0) ws->empty[bl] = mk ? 1 : 0;
        if (tid < NT) { float v = bias[tid]; out_logits[bl * NT + tid] = v; ws->lg[bl * NT + tid] = v; }
        return;
    }
    if (tid == 0) ws->empty[bl] = 0;

    #pragma unroll
    for (int k = 0; k < 3; k++) {
        int h = tid + k * 256;
        float wr = -3.0e38f;          // min_value <= all values, so -inf init equivalent
        for (int r = first; r <= last; r++)
            wr = fmaxf(wr, embs[(b * NP + r) * NH + h]);
        wrsh[h] = mk ? wr : 0.f;
    }
    __syncthreads();

    for (int t = w; t < NT; t += 4) {
        float acc = 0.f;
        #pragma unroll
        for (int j = 0; j < 12; j++) acc += wrsh[lane + j * 64] * W[(lane + j * 64) * NT + t];
        acc = dpp_add(acc);
        if (lane == 63) {
            float v = acc + bias[t];
            out_logits[bl * NT + t] = v;
            ws->lg[bl * NT + t]     = v;
        }
    }
}

// ---------------- Kernel 2: min-reduce + fixup + CRF (scaled linear domain) ----------
// 1 block, 4 waves, one wave per batch; lanes 0..8 hold A[tag] (exp-ed alpha).
__global__ __launch_bounds__(256) void kcrf(
    const int* __restrict__ labels, const int* __restrict__ sentlen,
    const float* __restrict__ W, const float* __restrict__ bias,
    const float* __restrict__ start_t, const float* __restrict__ end_t,
    const float* __restrict__ trans, WS* __restrict__ ws, float* __restrict__ out)
{
    __shared__ float em_s[NB * NL * NT + 16];   // raw logits
    __shared__ float p_s[NB * NL * NT + 16];    // P_i[c] = 2^((em_i[c]-em_i[0])*L2E); padded
    __shared__ float trs[NT * NT];              // log2-scaled
    __shared__ int   lab_s[NB * NL];
    __shared__ float llh[NB];
    __shared__ float colsum[NT];
    __shared__ float wmin[4];

    const int tid  = threadIdx.x;
    const int w    = tid >> 6;
    const int lane = tid & 63;

    // (1) register-stage all dependent loads up front (pipeline the latency)
    const float4* s4 = (const float4*)ws->lg;
    float4 lgv[4];
    #pragma unroll
    for (int r = 0; r < 4; r++) lgv[r] = s4[tid + r * 256];
    float4 lgt = (tid < 128) ? s4[tid + 1024] : make_float4(0, 0, 0, 0);
    int4  labv = (tid < 128) ? ((const int4*)labels)[tid] : make_int4(0, 0, 0, 0);
    float pmv  = fminf(ws->part[tid], ws->part[tid + 256]);
    float trv  = (tid < NT * NT) ? trans[tid] : 0.f;

    // (2) write staged data
    float4* d4 = (float4*)em_s;
    #pragma unroll
    for (int r = 0; r < 4; r++) d4[tid + r * 256] = lgv[r];
    if (tid < 128) d4[tid + 1024] = lgt;
    if (tid < 128) ((int4*)lab_s)[tid] = labv;
    if (tid < NT * NT) trs[tid] = trv * L2E;

    {   // global min from 512 partials
        float mv = dpp_fmin(pmv);
        if (lane == 63) wmin[w] = mv;
    }
    for (int t = w; t < NT; t += 4) {   // colsum(W) for minv fixup
        float s = 0.f;
        #pragma unroll
        for (int j = 0; j < 12; j++) s += W[(lane + j * 64) * NT + t];
        s = dpp_add(s);
        if (lane == 63) colsum[t] = s;
    }
    __syncthreads();
    const float minv = fminf(fminf(wmin[0], wmin[1]), fminf(wmin[2], wmin[3]));

    // fix flagged rows: minv*colsum + bias, or bias-only
    for (int r = tid; r < NBLK; r += 256) {
        if (ws->empty[r]) {
            #pragma unroll
            for (int t = 0; t < NT; t++) {
                float v = fmaf(minv, colsum[t], bias[t]);
                em_s[r * NT + t]    = v;
                out[1 + r * NT + t] = v;
            }
        }
    }
    __syncthreads();

    // (3) parallel precompute: P table (all threads), numerator + em0-scale sums (per wave)
    for (int j = tid; j < NB * NL * NT; j += 256) {
        float em0 = em_s[(j / 9) * 9];
        p_s[j] = exp2v((em_s[j] - em0) * L2E);
    }

    const int b   = w;
    const int c   = (lane < NT) ? lane : 0;
    const int len = sentlen[b];                 // masks == arange < sent_length
    const float* em  = em_s + b * NL * NT;
    const float* ps  = p_s + b * NL * NT;
    const int*   lab = lab_s + b * NL;

    float nsum = 0.f, ksum = 0.f;
    for (int i = 1 + lane; i < len; i += 64) {
        int tp = lab[i - 1], tc = lab[i];
        nsum = fmaf(em[i * NT + tc], L2E, nsum + trs[tp * NT + tc]);
        ksum = fmaf(em[i * NT], L2E, ksum);     // factored-out per-step scale
    }
    nsum = dpp_add(nsum);
    ksum = dpp_add(ksum);
    const float nsum_all = rdlane(nsum, 63);
    const float ksum_all = rdlane(ksum, 63);
    __syncthreads();

    // (4) serial recursion — scaled linear domain, no transcendentals on the chain
    float ecol[NT];
    #pragma unroll
    for (int p = 0; p < NT; p++) ecol[p] = exp2v(trs[p * NT + c]);   // E[p][c]

    float a0  = (start_t[c] + em[c]) * L2E;
    float a00 = rdlane(a0, 0);
    float A   = exp2v(a0 - a00);
    float Kf  = a00 + ksum_all;     // accumulated log2-scale (parallel part)
    int   Kl  = 0;                  // accumulated renorm exponents

    float p_nx = ps[NT + c];
    for (int i = 1; i < len; i++) {
        float p_cur = p_nx;
        p_nx = ps[(i + 1) * NT + c];            // pad covers overread at i = len-1
        float r0 = rdlane(A, 0), r1 = rdlane(A, 1), r2 = rdlane(A, 2);
        float r3 = rdlane(A, 3), r4 = rdlane(A, 4), r5 = rdlane(A, 5);
        float r6 = rdlane(A, 6), r7 = rdlane(A, 7), r8 = rdlane(A, 8);
        float s0 = r0 * ecol[0]; s0 = fmaf(r3, ecol[3], s0); s0 = fmaf(r6, ecol[6], s0);
        float s1 = r1 * ecol[1]; s1 = fmaf(r4, ecol[4], s1); s1 = fmaf(r7, ecol[7], s1);
        float s2 = r2 * ecol[2]; s2 = fmaf(r5, ecol[5], s2); s2 = fmaf(r8, ecol[8], s2);
        float S  = (s0 + s1) + s2;
        // renorm: exponent of max(prev A) — off the critical chain
        float mm = fmaxf(fmaxf(fmaxf(r0, r1), fmaxf(r2, r3)),
                         fmaxf(fmaxf(r4, r5), fmaxf(r6, r7)));
        mm = fmaxf(mm, r8);
        int k = (__float_as_int(mm) >> 23) - 127;
        float SP = S * p_cur;
        int nk = -k;
        asm("v_ldexp_f32 %0, %1, %2" : "=v"(A) : "v"(SP), "v"(nk));
        Kl += k;
    }

    // (5) denominator + loss
    float xv = A * exp2v(end_t[c] * L2E);
    if (lane == 0) {
        float s = xv;
        #pragma unroll
        for (int p = 1; p < NT; p++) s += rdlane(xv, p);
        float lg;
        asm("v_log_f32 %0, %1" : "=v"(lg) : "v"(s));
        float den = lg + Kf + (float)Kl;
        int   t0  = lab[0];
        float num = nsum_all + (start_t[t0] + em[t0]) * L2E + end_t[lab[len - 1]] * L2E;
        llh[b] = (num - den) * LN2;
    }
    __syncthreads();
    if (tid == 0) out[0] = -(llh[0] + llh[1] + llh[2] + llh[3]);
}

extern "C" void kernel_launch(void* const* d_in, const int* in_sizes, int n_in,
                              void* d_out, int out_size, void* d_ws, size_t ws_size,
                              hipStream_t stream) {
    const float* embs    = (const float*)d_in[0];
    const void*  p2w     = d_in[1];
    const void*  masks   = d_in[2];
    const int*   labels  = (const int*)d_in[3];
    const int*   sentlen = (const int*)d_in[4];
    const float* W       = (const float*)d_in[5];
    const float* bias    = (const float*)d_in[6];
    const float* start_t = (const float*)d_in[7];
    const float* end_t   = (const float*)d_in[8];
    const float* trans   = (const float*)d_in[9];

    float* out = (float*)d_out;        // out[0] = loss, out[1..] = logits (B,L,T)
    WS*    ws  = (WS*)d_ws;

    klogits<<<NBLK, 256, 0, stream>>>(embs, p2w, masks, W, bias, out + 1, ws);
    kcrf<<<1, 256, 0, stream>>>(labels, sentlen, W, bias, start_t, end_t, trans, ws, out);
}